// Round 1
// baseline (308.312 us; speedup 1.0000x reference)
//
#include <hip/hip_runtime.h>
#include <hip/hip_bf16.h>
#include <stdint.h>

// SpatialMHA: B=64 S=256 E=1024 H=16 D=64
// qkv = x @ Win^T + bin ; attn with additive spatial bias ; out = x + ctx @ Wout^T + bout

typedef __attribute__((ext_vector_type(8))) __bf16 bf16x8;
typedef __attribute__((ext_vector_type(4))) float f32x4;

#define DEVI static __device__ __forceinline__

DEVI unsigned short f2bf(float f) {           // fp32 -> bf16 round-to-nearest-even
  union { float f; unsigned u; } x; x.f = f;
  unsigned r = x.u + 0x7fffu + ((x.u >> 16) & 1u);
  return (unsigned short)(r >> 16);
}

typedef unsigned int __attribute__((address_space(1))) u32_g;
typedef unsigned int __attribute__((address_space(3))) u32_l;

DEVI void g2l16(const unsigned short* g, unsigned short* l) {
  // async global->LDS, 16B per lane; LDS dest = wave-uniform base + lane*16
  __builtin_amdgcn_global_load_lds((const u32_g*)g, (u32_l*)l, 16, 0, 0);
}

// ---------------------------------------------------------------- fp32->bf16
__global__ __launch_bounds__(256) void cvt_kernel(const float* __restrict__ s,
                                                  unsigned short* __restrict__ d, int n) {
  int i = (blockIdx.x * 256 + threadIdx.x) * 4;
  if (i >= n) return;
  float4 v = *(const float4*)(s + i);
  ushort4 o;
  o.x = f2bf(v.x); o.y = f2bf(v.y); o.z = f2bf(v.z); o.w = f2bf(v.w);
  *(ushort4*)(d + i) = o;
}

// ---------------------------------------------------------------- GEMM (B^T layout)
// C[m,n] = sum_k A[m,k]*Bw[n,k];  A:[M,1024] bf16, Bw:[N,1024] bf16, both K-contiguous.
// 128x128 tile, BK=64, 4 waves (2x2), each wave 64x64 via 4x4 mfma_16x16x32 frags.
// EPI=0: QKV epilogue (+bias, scatter Q/K [B,H,S,D] and V^T [B,H,D,S] as bf16)
// EPI=1: out-proj epilogue (+bias +residual x, fp32 out)
template <int EPI>
__global__ __launch_bounds__(256, 2)
void gemm_bt(const unsigned short* __restrict__ A,
             const unsigned short* __restrict__ Bw,
             const float* __restrict__ bias,
             unsigned short* __restrict__ Qo,
             unsigned short* __restrict__ Ko,
             unsigned short* __restrict__ VTo,
             const float* __restrict__ Xres,
             float* __restrict__ Out) {
  __shared__ unsigned short As[8192];   // [128][64] bf16, 16KB
  __shared__ unsigned short Bs[8192];
  const int lane = threadIdx.x & 63, wave = threadIdx.x >> 6;
  const int l15 = lane & 15, lg = lane >> 4;
  const int wr = wave >> 1, wc = wave & 1;
  const int am0 = blockIdx.x * 128, bn0 = blockIdx.y * 128;

  f32x4 acc[4][4] = {};

  for (int kt = 0; kt < 16; ++kt) {
    const int k0 = kt * 64;
#pragma unroll
    for (int i = 0; i < 4; ++i) {
      const int seg = wave * 4 + i;
      const int off = seg * 1024 + lane * 16;   // byte offset within 16KB tile
      const int row = off >> 7;                 // row stride 128B
      const int ke  = (off & 127) >> 1;         // element within row
      g2l16(A  + (size_t)(am0 + row) * 1024 + k0 + ke, &As[seg * 512]);
      g2l16(Bw + (size_t)(bn0 + row) * 1024 + k0 + ke, &Bs[seg * 512]);
    }
    __syncthreads();   // drains vmcnt(0) for global_load_lds
#pragma unroll
    for (int kk = 0; kk < 2; ++kk) {
      bf16x8 a[4], b[4];
#pragma unroll
      for (int mf = 0; mf < 4; ++mf)
        a[mf] = *(const bf16x8*)&As[(wr * 64 + mf * 16 + l15) * 64 + kk * 32 + lg * 8];
#pragma unroll
      for (int nf = 0; nf < 4; ++nf)
        b[nf] = *(const bf16x8*)&Bs[(wc * 64 + nf * 16 + l15) * 64 + kk * 32 + lg * 8];
#pragma unroll
      for (int mf = 0; mf < 4; ++mf)
#pragma unroll
        for (int nf = 0; nf < 4; ++nf)
          acc[mf][nf] = __builtin_amdgcn_mfma_f32_16x16x32_bf16(a[mf], b[nf], acc[mf][nf], 0, 0, 0);
    }
    __syncthreads();
  }

  // C frag mapping: col = l15 (+16*nf +64*wc +bn0), row = lg*4+r (+16*mf +64*wr +am0)
  if (EPI == 0) {
#pragma unroll
    for (int nf = 0; nf < 4; ++nf) {
      const int col = bn0 + wc * 64 + nf * 16 + l15;   // 0..3071
      const int which = col >> 10;                     // 0=Q 1=K 2=V (uniform per block)
      const int e = col & 1023;
      const int hh = e >> 6, dd = e & 63;
      const float bv = bias[col];
#pragma unroll
      for (int mf = 0; mf < 4; ++mf) {
        const int row0 = am0 + wr * 64 + mf * 16 + lg * 4;  // multiple of 4
        const int bb = row0 >> 8;
        const int s0 = row0 & 255;
        if (which == 2) {
          unsigned long long pk = 0;
#pragma unroll
          for (int r = 0; r < 4; ++r)
            pk |= (unsigned long long)f2bf(acc[mf][nf][r] + bv) << (16 * r);
          *(unsigned long long*)&VTo[((size_t)(bb * 16 + hh) * 64 + dd) * 256 + s0] = pk;
        } else {
          unsigned short* dst = (which == 0) ? Qo : Ko;
#pragma unroll
          for (int r = 0; r < 4; ++r)
            dst[((size_t)(bb * 16 + hh) * 256 + s0 + r) * 64 + dd] = f2bf(acc[mf][nf][r] + bv);
        }
      }
    }
  } else {
#pragma unroll
    for (int nf = 0; nf < 4; ++nf) {
      const int col = bn0 + wc * 64 + nf * 16 + l15;
      const float bv = bias[col];
#pragma unroll
      for (int mf = 0; mf < 4; ++mf) {
#pragma unroll
        for (int r = 0; r < 4; ++r) {
          const int row = am0 + wr * 64 + mf * 16 + lg * 4 + r;
          const size_t idx = (size_t)row * 1024 + col;
          Out[idx] = Xres[idx] + acc[mf][nf][r] + bv;
        }
      }
    }
  }
}

// ---------------------------------------------------------------- fused attention
// One block per (b,h); 4 waves, each owns 64 q rows. FA2 online softmax over 4 key
// chunks of 64. Scores computed transposed: S^T = mfma(A=K, B=Q) -> row=key, col=q,
// so the row-softmax reduces with just shfl_xor 16/32. P staged per-wave in padded
// LDS (stride 160B -> 4-way banks) to transpose for the PV mfma A-operand.
__global__ __launch_bounds__(256) void attn_kernel(const unsigned short* __restrict__ Qg,
                                                   const unsigned short* __restrict__ Kg,
                                                   const unsigned short* __restrict__ VTg,
                                                   const float* __restrict__ bias,
                                                   unsigned short* __restrict__ ctx) {
  __shared__ unsigned short P[4][64][80];   // per-wave private [q][k], pad 64->80
  const int lane = threadIdx.x & 63, wave = threadIdx.x >> 6;
  const int l15 = lane & 15, lg = lane >> 4;
  const int bh = blockIdx.x;
  const int bb = bh >> 4, hh = bh & 15;
  const size_t base = (size_t)bh * (256 * 64);
  const int q0 = wave * 64;

  // Q as B-operand fragments: lane holds Q[q0+qi*16+l15][kc*32+lg*8 .. +8]
  bf16x8 qfr[4][2];
#pragma unroll
  for (int qi = 0; qi < 4; ++qi)
#pragma unroll
    for (int kc = 0; kc < 2; ++kc)
      qfr[qi][kc] = *(const bf16x8*)&Qg[base + (size_t)(q0 + qi * 16 + l15) * 64 + kc * 32 + lg * 8];

  f32x4 o[4][4] = {};
  float mrow[4], lrow[4];
#pragma unroll
  for (int i = 0; i < 4; ++i) { mrow[i] = -1e30f; lrow[i] = 0.f; }

  for (int c = 0; c < 4; ++c) {
    // K as A-operand fragments
    bf16x8 kfr[4][2];
#pragma unroll
    for (int kr = 0; kr < 4; ++kr)
#pragma unroll
      for (int kc = 0; kc < 2; ++kc)
        kfr[kr][kc] = *(const bf16x8*)&Kg[base + (size_t)(c * 64 + kr * 16 + l15) * 64 + kc * 32 + lg * 8];

    // S^T chunk [64k x 64q]
    f32x4 s[4][4] = {};
#pragma unroll
    for (int kr = 0; kr < 4; ++kr)
#pragma unroll
      for (int qi = 0; qi < 4; ++qi)
#pragma unroll
        for (int kc = 0; kc < 2; ++kc)
          s[kr][qi] = __builtin_amdgcn_mfma_f32_16x16x32_bf16(kfr[kr][kc], qfr[qi][kc], s[kr][qi], 0, 0, 0);

    // scale + spatial bias; chunk max per q-column
    float cmax[4];
#pragma unroll
    for (int qi = 0; qi < 4; ++qi) cmax[qi] = -1e30f;
#pragma unroll
    for (int kr = 0; kr < 4; ++kr)
#pragma unroll
      for (int qi = 0; qi < 4; ++qi)
#pragma unroll
        for (int r = 0; r < 4; ++r) {
          const int krow = c * 64 + kr * 16 + lg * 4 + r;
          const int qcol = q0 + qi * 16 + l15;
          float v = s[kr][qi][r] * 0.125f + bias[qcol * 256 + krow];
          s[kr][qi][r] = v;
          cmax[qi] = fmaxf(cmax[qi], v);
        }
#pragma unroll
    for (int qi = 0; qi < 4; ++qi) {
      cmax[qi] = fmaxf(cmax[qi], __shfl_xor(cmax[qi], 16, 64));
      cmax[qi] = fmaxf(cmax[qi], __shfl_xor(cmax[qi], 32, 64));
    }
    float resc[4], csum[4];
#pragma unroll
    for (int qi = 0; qi < 4; ++qi) {
      float mn = fmaxf(mrow[qi], cmax[qi]);
      resc[qi] = __expf(mrow[qi] - mn);
      mrow[qi] = mn;
      csum[qi] = 0.f;
    }
#pragma unroll
    for (int kr = 0; kr < 4; ++kr)
#pragma unroll
      for (int qi = 0; qi < 4; ++qi)
#pragma unroll
        for (int r = 0; r < 4; ++r) {
          float e = __expf(s[kr][qi][r] - mrow[qi]);
          s[kr][qi][r] = e;
          csum[qi] += e;
        }
#pragma unroll
    for (int qi = 0; qi < 4; ++qi) {
      csum[qi] += __shfl_xor(csum[qi], 16, 64);
      csum[qi] += __shfl_xor(csum[qi], 32, 64);
      lrow[qi] = lrow[qi] * resc[qi] + csum[qi];
    }

    // P -> LDS transposed to [q][k] (per-wave private; within-wave sync only)
#pragma unroll
    for (int kr = 0; kr < 4; ++kr)
#pragma unroll
      for (int qi = 0; qi < 4; ++qi)
#pragma unroll
        for (int r = 0; r < 4; ++r)
          P[wave][qi * 16 + l15][kr * 16 + lg * 4 + r] = f2bf(s[kr][qi][r]);
    asm volatile("s_waitcnt lgkmcnt(0)" ::: "memory");

    // rescale O: factor for q-row = lg*4+r lives in lane (lg*4+r) of resc[qrf]
#pragma unroll
    for (int qrf = 0; qrf < 4; ++qrf)
#pragma unroll
      for (int r = 0; r < 4; ++r) {
        float f = __shfl(resc[qrf], lg * 4 + r, 64);
#pragma unroll
        for (int df = 0; df < 4; ++df) o[qrf][df][r] *= f;
      }

    // PV: A = P[q][k] from LDS, B = V[k][d] read from V^T (contiguous)
    bf16x8 vb[2][4], pa[4][2];
#pragma unroll
    for (int kc = 0; kc < 2; ++kc)
#pragma unroll
      for (int df = 0; df < 4; ++df)
        vb[kc][df] = *(const bf16x8*)&VTg[base + (size_t)(df * 16 + l15) * 256 + c * 64 + kc * 32 + lg * 8];
#pragma unroll
    for (int qrf = 0; qrf < 4; ++qrf)
#pragma unroll
      for (int kc = 0; kc < 2; ++kc)
        pa[qrf][kc] = *(const bf16x8*)&P[wave][qrf * 16 + l15][kc * 32 + lg * 8];
#pragma unroll
    for (int qrf = 0; qrf < 4; ++qrf)
#pragma unroll
      for (int df = 0; df < 4; ++df)
#pragma unroll
        for (int kc = 0; kc < 2; ++kc)
          o[qrf][df] = __builtin_amdgcn_mfma_f32_16x16x32_bf16(pa[qrf][kc], vb[kc][df], o[qrf][df], 0, 0, 0);
  }

  // normalize and write ctx [B,S,E] bf16
#pragma unroll
  for (int qrf = 0; qrf < 4; ++qrf)
#pragma unroll
    for (int r = 0; r < 4; ++r) {
      float li = __shfl(lrow[qrf], lg * 4 + r, 64);
      float inv = 1.0f / li;
      const int q = q0 + qrf * 16 + lg * 4 + r;
#pragma unroll
      for (int df = 0; df < 4; ++df) {
        const int d = df * 16 + l15;
        ctx[((size_t)(bb * 256 + q) * 16 + hh) * 64 + d] = f2bf(o[qrf][df][r] * inv);
      }
    }
}

// ---------------------------------------------------------------- launch
extern "C" void kernel_launch(void* const* d_in, const int* in_sizes, int n_in,
                              void* d_out, int out_size, void* d_ws, size_t ws_size,
                              hipStream_t stream) {
  const float* x  = (const float*)d_in[0];
  const float* wi = (const float*)d_in[1];
  const float* bi = (const float*)d_in[2];
  const float* wo = (const float*)d_in[3];
  const float* bo = (const float*)d_in[4];
  const float* sb = (const float*)d_in[5];
  float* out = (float*)d_out;

  char* ws = (char*)d_ws;
  // ws layout (bytes): x_bf/ctx 33554432 | w_in 6291456 | w_out 2097152 | Q | K | VT
  unsigned short* xbf  = (unsigned short*)(ws);
  unsigned short* winb = (unsigned short*)(ws + 33554432u);
  unsigned short* wob  = (unsigned short*)(ws + 39845888u);
  unsigned short* Qb   = (unsigned short*)(ws + 41943040u);
  unsigned short* Kb   = (unsigned short*)(ws + 75497472u);
  unsigned short* VTb  = (unsigned short*)(ws + 109051904u);
  unsigned short* ctx  = xbf;   // x_bf dead after QKV GEMM; reuse for ctx

  cvt_kernel<<<16384, 256, 0, stream>>>(x, xbf, 16777216);
  cvt_kernel<<<3072, 256, 0, stream>>>(wi, winb, 3145728);
  cvt_kernel<<<1024, 256, 0, stream>>>(wo, wob, 1048576);

  // QKV: M=16384 N=3072 K=1024
  gemm_bt<0><<<dim3(128, 24), 256, 0, stream>>>(xbf, winb, bi, Qb, Kb, VTb, nullptr, nullptr);

  // attention: one block per (b,h)
  attn_kernel<<<1024, 256, 0, stream>>>(Qb, Kb, VTb, sb, ctx);

  // out-proj + residual: M=16384 N=1024 K=1024
  gemm_bt<1><<<dim3(128, 8), 256, 0, stream>>>(ctx, wob, bo, nullptr, nullptr, nullptr, x, out);
}

// Round 2
// 292.771 us; speedup vs baseline: 1.0531x; 1.0531x over previous
//
#include <hip/hip_runtime.h>
#include <hip/hip_bf16.h>
#include <stdint.h>

// SpatialMHA: B=64 S=256 E=1024 H=16 D=64
// qkv = x @ Win^T + bin ; attn with additive spatial bias ; out = x + ctx @ Wout^T + bout

typedef __attribute__((ext_vector_type(8))) __bf16 bf16x8;
typedef __attribute__((ext_vector_type(4))) float f32x4;

#define DEVI static __device__ __forceinline__

DEVI unsigned short f2bf(float f) {           // fp32 -> bf16 round-to-nearest-even
  union { float f; unsigned u; } x; x.f = f;
  unsigned r = x.u + 0x7fffu + ((x.u >> 16) & 1u);
  return (unsigned short)(r >> 16);
}

typedef unsigned int __attribute__((address_space(1))) u32_g;
typedef unsigned int __attribute__((address_space(3))) u32_l;

DEVI void g2l16(const unsigned short* g, unsigned short* l) {
  // async global->LDS, 16B per lane; LDS dest = wave-uniform base + lane*16
  __builtin_amdgcn_global_load_lds((const u32_g*)g, (u32_l*)l, 16, 0, 0);
}

// ---------------------------------------------------------------- fp32->bf16
__global__ __launch_bounds__(256) void cvt_kernel(const float* __restrict__ s,
                                                  unsigned short* __restrict__ d, int n) {
  int i = (blockIdx.x * 256 + threadIdx.x) * 4;
  if (i >= n) return;
  float4 v = *(const float4*)(s + i);
  ushort4 o;
  o.x = f2bf(v.x); o.y = f2bf(v.y); o.z = f2bf(v.z); o.w = f2bf(v.w);
  *(ushort4*)(d + i) = o;
}

// ---------------------------------------------------------------- 256x256 GEMM (B^T layout)
// C[m,n] = sum_k A[m,k]*Bw[n,k]; K=1024 fixed. 8 waves (2M x 4N), per-wave 128x64 C.
// K processed in 32 slabs of 32; LDS = 4-slot ring per operand (4x16KB A + 4x16KB B = 128KB).
// Per phase: 12 ds_read_b128 || stage slab p+3 (4 global_load_lds) -> vmcnt(8) ->
// lgkmcnt(0) -> s_barrier -> setprio(1) + 32 MFMA.  Counted vmcnt keeps 2 phases of
// loads in flight across barriers (T3+T4); XOR swizzle ((row>>1)&3)<<4 on the 16B slot
// within each 64B row makes frag reads bank-conflict-free (T2); same involution applied
// to the global source so global_load_lds' linear LDS write stores swizzled data (m173).
template <int EPI>
__global__ __launch_bounds__(512, 2)
void gemm8(const unsigned short* __restrict__ A,
           const unsigned short* __restrict__ Bw,
           const float* __restrict__ bias,
           unsigned short* __restrict__ Qo,
           unsigned short* __restrict__ Ko,
           unsigned short* __restrict__ VTo,
           const float* __restrict__ Xres,
           float* __restrict__ Out) {
  extern __shared__ unsigned short lds[];   // [0,32768): A ring, [32768,65536): B ring (elems)
  const int lane = threadIdx.x & 63, wid = threadIdx.x >> 6;
  const int l15 = lane & 15, lg = lane >> 4;
  const int wr = wid >> 2, wcn = wid & 3;
  const int am0 = blockIdx.x * 256, bn0 = blockIdx.y * 256;

  const int srow0 = wid * 16 + (lane >> 2);   // staging row (+ j*128)
  const int scb0  = (lane & 3) * 16;          // staging linear col-byte

  f32x4 acc[8][4] = {};

#define SWZ(row) ((((row) >> 1) & 3) << 4)

#define STAGE(s) { \
    const int slot_ = (s) & 3; \
    _Pragma("unroll") \
    for (int j = 0; j < 2; ++j) { \
      const int row_ = j * 128 + srow0; \
      const int cs_ = scb0 ^ SWZ(row_); \
      g2l16(A  + (size_t)(am0 + row_) * 1024 + (s) * 32 + (cs_ >> 1), \
            &lds[slot_ * 8192 + j * 4096 + wid * 512]); \
      g2l16(Bw + (size_t)(bn0 + row_) * 1024 + (s) * 32 + (cs_ >> 1), \
            &lds[32768 + slot_ * 8192 + j * 4096 + wid * 512]); \
    } }

#define LOADFRAGS(p) \
    bf16x8 a[8], b[4]; \
    { const unsigned short* As_ = &lds[((p) & 3) * 8192]; \
      const unsigned short* Bs_ = &lds[32768 + ((p) & 3) * 8192]; \
      _Pragma("unroll") \
      for (int mf = 0; mf < 8; ++mf) { \
        const int row_ = wr * 128 + mf * 16 + l15; \
        a[mf] = *(const bf16x8*)((const char*)As_ + row_ * 64 + ((lg * 16) ^ SWZ(row_))); \
      } \
      _Pragma("unroll") \
      for (int nf = 0; nf < 4; ++nf) { \
        const int row_ = wcn * 64 + nf * 16 + l15; \
        b[nf] = *(const bf16x8*)((const char*)Bs_ + row_ * 64 + ((lg * 16) ^ SWZ(row_))); \
      } }

#define MFMAS() { \
    __builtin_amdgcn_s_setprio(1); \
    _Pragma("unroll") \
    for (int mf = 0; mf < 8; ++mf) \
      _Pragma("unroll") \
      for (int nf = 0; nf < 4; ++nf) \
        acc[mf][nf] = __builtin_amdgcn_mfma_f32_16x16x32_bf16(a[mf], b[nf], acc[mf][nf], 0, 0, 0); \
    __builtin_amdgcn_s_setprio(0); }

  // prologue: stage slabs 0..2 (12 issues/wave), wait slab0, handshake
  STAGE(0) STAGE(1) STAGE(2)
  asm volatile("s_waitcnt vmcnt(8)" ::: "memory");
  __builtin_amdgcn_s_barrier();

#pragma unroll 4
  for (int p = 0; p < 29; ++p) {
    LOADFRAGS(p)
    STAGE(p + 3)
    asm volatile("s_waitcnt vmcnt(8)" ::: "memory");   // slab p+1 landed after barrier
    asm volatile("s_waitcnt lgkmcnt(0)" ::: "memory"); // my reads done -> slot reuse safe
    __builtin_amdgcn_s_barrier();
    MFMAS()
  }
  { LOADFRAGS(29)
    asm volatile("s_waitcnt vmcnt(4)" ::: "memory");
    asm volatile("s_waitcnt lgkmcnt(0)" ::: "memory");
    __builtin_amdgcn_s_barrier();
    MFMAS() }
  { LOADFRAGS(30)
    asm volatile("s_waitcnt vmcnt(0)" ::: "memory");
    asm volatile("s_waitcnt lgkmcnt(0)" ::: "memory");
    __builtin_amdgcn_s_barrier();
    MFMAS() }
  { LOADFRAGS(31)
    MFMAS() }

  // C frag mapping: col = bn0 + wcn*64 + nf*16 + l15 ; row = am0 + wr*128 + mf*16 + lg*4 + r
  if (EPI == 0) {
#pragma unroll
    for (int nf = 0; nf < 4; ++nf) {
      const int col = bn0 + wcn * 64 + nf * 16 + l15;   // 0..3071
      const int which = col >> 10;                      // 0=Q 1=K 2=V (uniform per block)
      const int e = col & 1023;
      const int hh = e >> 6, dd = e & 63;
      const float bv = bias[col];
#pragma unroll
      for (int mf = 0; mf < 8; ++mf) {
        const int row0 = am0 + wr * 128 + mf * 16 + lg * 4;  // multiple of 4
        const int bb = row0 >> 8;
        const int s0 = row0 & 255;
        if (which == 2) {
          unsigned long long pk = 0;
#pragma unroll
          for (int r = 0; r < 4; ++r)
            pk |= (unsigned long long)f2bf(acc[mf][nf][r] + bv) << (16 * r);
          *(unsigned long long*)&VTo[((size_t)(bb * 16 + hh) * 64 + dd) * 256 + s0] = pk;
        } else {
          unsigned short* dst = (which == 0) ? Qo : Ko;
#pragma unroll
          for (int r = 0; r < 4; ++r)
            dst[((size_t)(bb * 16 + hh) * 256 + s0 + r) * 64 + dd] = f2bf(acc[mf][nf][r] + bv);
        }
      }
    }
  } else {
#pragma unroll
    for (int nf = 0; nf < 4; ++nf) {
      const int col = bn0 + wcn * 64 + nf * 16 + l15;
      const float bv = bias[col];
#pragma unroll
      for (int mf = 0; mf < 8; ++mf) {
#pragma unroll
        for (int r = 0; r < 4; ++r) {
          const int row = am0 + wr * 128 + mf * 16 + lg * 4 + r;
          const size_t idx = (size_t)row * 1024 + col;
          Out[idx] = Xres[idx] + acc[mf][nf][r] + bv;
        }
      }
    }
  }
#undef SWZ
#undef STAGE
#undef LOADFRAGS
#undef MFMAS
}

// ---------------------------------------------------------------- fused attention
// One block per (b,h); 4 waves, each owns 64 q rows. FA2 online softmax over 4 key
// chunks of 64. Scores computed transposed: S^T = mfma(A=K, B=Q) -> row=key, col=q,
// so the row-softmax reduces with just shfl_xor 16/32. P staged per-wave in padded
// LDS (stride 160B -> 4-way banks) to transpose for the PV mfma A-operand.
__global__ __launch_bounds__(256) void attn_kernel(const unsigned short* __restrict__ Qg,
                                                   const unsigned short* __restrict__ Kg,
                                                   const unsigned short* __restrict__ VTg,
                                                   const float* __restrict__ bias,
                                                   unsigned short* __restrict__ ctx) {
  __shared__ unsigned short P[4][64][80];   // per-wave private [q][k], pad 64->80
  const int lane = threadIdx.x & 63, wave = threadIdx.x >> 6;
  const int l15 = lane & 15, lg = lane >> 4;
  const int bh = blockIdx.x;
  const int bb = bh >> 4, hh = bh & 15;
  const size_t base = (size_t)bh * (256 * 64);
  const int q0 = wave * 64;

  // Q as B-operand fragments: lane holds Q[q0+qi*16+l15][kc*32+lg*8 .. +8]
  bf16x8 qfr[4][2];
#pragma unroll
  for (int qi = 0; qi < 4; ++qi)
#pragma unroll
    for (int kc = 0; kc < 2; ++kc)
      qfr[qi][kc] = *(const bf16x8*)&Qg[base + (size_t)(q0 + qi * 16 + l15) * 64 + kc * 32 + lg * 8];

  f32x4 o[4][4] = {};
  float mrow[4], lrow[4];
#pragma unroll
  for (int i = 0; i < 4; ++i) { mrow[i] = -1e30f; lrow[i] = 0.f; }

  for (int c = 0; c < 4; ++c) {
    // K as A-operand fragments
    bf16x8 kfr[4][2];
#pragma unroll
    for (int kr = 0; kr < 4; ++kr)
#pragma unroll
      for (int kc = 0; kc < 2; ++kc)
        kfr[kr][kc] = *(const bf16x8*)&Kg[base + (size_t)(c * 64 + kr * 16 + l15) * 64 + kc * 32 + lg * 8];

    // S^T chunk [64k x 64q]
    f32x4 s[4][4] = {};
#pragma unroll
    for (int kr = 0; kr < 4; ++kr)
#pragma unroll
      for (int qi = 0; qi < 4; ++qi)
#pragma unroll
        for (int kc = 0; kc < 2; ++kc)
          s[kr][qi] = __builtin_amdgcn_mfma_f32_16x16x32_bf16(kfr[kr][kc], qfr[qi][kc], s[kr][qi], 0, 0, 0);

    // scale + spatial bias (float4 over r: krow consecutive); chunk max per q-column
    float cmax[4];
#pragma unroll
    for (int qi = 0; qi < 4; ++qi) cmax[qi] = -1e30f;
#pragma unroll
    for (int kr = 0; kr < 4; ++kr)
#pragma unroll
      for (int qi = 0; qi < 4; ++qi) {
        const int krow0 = c * 64 + kr * 16 + lg * 4;
        const int qcol = q0 + qi * 16 + l15;
        const f32x4 b4 = *(const f32x4*)&bias[qcol * 256 + krow0];
#pragma unroll
        for (int r = 0; r < 4; ++r) {
          float v = s[kr][qi][r] * 0.125f + b4[r];
          s[kr][qi][r] = v;
          cmax[qi] = fmaxf(cmax[qi], v);
        }
      }
#pragma unroll
    for (int qi = 0; qi < 4; ++qi) {
      cmax[qi] = fmaxf(cmax[qi], __shfl_xor(cmax[qi], 16, 64));
      cmax[qi] = fmaxf(cmax[qi], __shfl_xor(cmax[qi], 32, 64));
    }
    float resc[4], csum[4];
#pragma unroll
    for (int qi = 0; qi < 4; ++qi) {
      float mn = fmaxf(mrow[qi], cmax[qi]);
      resc[qi] = __expf(mrow[qi] - mn);
      mrow[qi] = mn;
      csum[qi] = 0.f;
    }
#pragma unroll
    for (int kr = 0; kr < 4; ++kr)
#pragma unroll
      for (int qi = 0; qi < 4; ++qi)
#pragma unroll
        for (int r = 0; r < 4; ++r) {
          float e = __expf(s[kr][qi][r] - mrow[qi]);
          s[kr][qi][r] = e;
          csum[qi] += e;
        }
#pragma unroll
    for (int qi = 0; qi < 4; ++qi) {
      csum[qi] += __shfl_xor(csum[qi], 16, 64);
      csum[qi] += __shfl_xor(csum[qi], 32, 64);
      lrow[qi] = lrow[qi] * resc[qi] + csum[qi];
    }

    // P -> LDS transposed to [q][k] (per-wave private; within-wave sync only)
#pragma unroll
    for (int kr = 0; kr < 4; ++kr)
#pragma unroll
      for (int qi = 0; qi < 4; ++qi)
#pragma unroll
        for (int r = 0; r < 4; ++r)
          P[wave][qi * 16 + l15][kr * 16 + lg * 4 + r] = f2bf(s[kr][qi][r]);
    asm volatile("s_waitcnt lgkmcnt(0)" ::: "memory");

    // rescale O: factor for q-row = lg*4+r lives in lane (lg*4+r) of resc[qrf]
#pragma unroll
    for (int qrf = 0; qrf < 4; ++qrf)
#pragma unroll
      for (int r = 0; r < 4; ++r) {
        float f = __shfl(resc[qrf], lg * 4 + r, 64);
#pragma unroll
        for (int df = 0; df < 4; ++df) o[qrf][df][r] *= f;
      }

    // PV: A = P[q][k] from LDS, B = V[k][d] read from V^T (contiguous)
    bf16x8 vb[2][4], pa[4][2];
#pragma unroll
    for (int kc = 0; kc < 2; ++kc)
#pragma unroll
      for (int df = 0; df < 4; ++df)
        vb[kc][df] = *(const bf16x8*)&VTg[base + (size_t)(df * 16 + l15) * 256 + c * 64 + kc * 32 + lg * 8];
#pragma unroll
    for (int qrf = 0; qrf < 4; ++qrf)
#pragma unroll
      for (int kc = 0; kc < 2; ++kc)
        pa[qrf][kc] = *(const bf16x8*)&P[wave][qrf * 16 + l15][kc * 32 + lg * 8];
#pragma unroll
    for (int qrf = 0; qrf < 4; ++qrf)
#pragma unroll
      for (int df = 0; df < 4; ++df)
#pragma unroll
        for (int kc = 0; kc < 2; ++kc)
          o[qrf][df] = __builtin_amdgcn_mfma_f32_16x16x32_bf16(pa[qrf][kc], vb[kc][df], o[qrf][df], 0, 0, 0);
  }

  // normalize and write ctx [B,S,E] bf16
#pragma unroll
  for (int qrf = 0; qrf < 4; ++qrf)
#pragma unroll
    for (int r = 0; r < 4; ++r) {
      float li = __shfl(lrow[qrf], lg * 4 + r, 64);
      float inv = 1.0f / li;
      const int q = q0 + qrf * 16 + lg * 4 + r;
#pragma unroll
      for (int df = 0; df < 4; ++df) {
        const int d = df * 16 + l15;
        ctx[((size_t)(bb * 256 + q) * 16 + hh) * 64 + d] = f2bf(o[qrf][df][r] * inv);
      }
    }
}

// ---------------------------------------------------------------- launch
extern "C" void kernel_launch(void* const* d_in, const int* in_sizes, int n_in,
                              void* d_out, int out_size, void* d_ws, size_t ws_size,
                              hipStream_t stream) {
  const float* x  = (const float*)d_in[0];
  const float* wi = (const float*)d_in[1];
  const float* bi = (const float*)d_in[2];
  const float* wo = (const float*)d_in[3];
  const float* bo = (const float*)d_in[4];
  const float* sb = (const float*)d_in[5];
  float* out = (float*)d_out;

  char* ws = (char*)d_ws;
  // ws layout (bytes): x_bf/ctx 33554432 | w_in 6291456 | w_out 2097152 | Q | K | VT
  unsigned short* xbf  = (unsigned short*)(ws);
  unsigned short* winb = (unsigned short*)(ws + 33554432u);
  unsigned short* wob  = (unsigned short*)(ws + 39845888u);
  unsigned short* Qb   = (unsigned short*)(ws + 41943040u);
  unsigned short* Kb   = (unsigned short*)(ws + 75497472u);
  unsigned short* VTb  = (unsigned short*)(ws + 109051904u);
  unsigned short* ctx  = xbf;   // x_bf dead after QKV GEMM; reuse for ctx

  // 128KB dynamic LDS needs the attribute raised past the 64KB default
  (void)hipFuncSetAttribute(reinterpret_cast<const void*>(gemm8<0>),
                            hipFuncAttributeMaxDynamicSharedMemorySize, 131072);
  (void)hipFuncSetAttribute(reinterpret_cast<const void*>(gemm8<1>),
                            hipFuncAttributeMaxDynamicSharedMemorySize, 131072);

  cvt_kernel<<<16384, 256, 0, stream>>>(x, xbf, 16777216);
  cvt_kernel<<<3072, 256, 0, stream>>>(wi, winb, 3145728);
  cvt_kernel<<<1024, 256, 0, stream>>>(wo, wob, 1048576);

  // QKV: M=16384 N=3072 K=1024
  gemm8<0><<<dim3(64, 12), 512, 131072, stream>>>(xbf, winb, bi, Qb, Kb, VTb, nullptr, nullptr);

  // attention: one block per (b,h)
  attn_kernel<<<1024, 256, 0, stream>>>(Qb, Kb, VTb, sb, ctx);

  // out-proj + residual: M=16384 N=1024 K=1024
  gemm8<1><<<dim3(64, 4), 512, 131072, stream>>>(ctx, wob, bo, nullptr, nullptr, nullptr, x, out);
}